// Round 11
// baseline (621.480 us; speedup 1.0000x reference)
//
#include <hip/hip_runtime.h>
#include <hip/hip_cooperative_groups.h>

#define BB 2
#define NN 2000
#define FF 64
#define DD 128
#define NH 4
#define HNZ 3
#define DEEP 384
#define NSEG 8
#define SEGSTRIDE 256
#define HTPAD 2048
#define SEGTOT (BB * NN * DD)
#define DENTOT (BB * NN * NH)
#define LOG2E 1.44269504f
#define SMSZ 1600

namespace cg = cooperative_groups;

typedef __attribute__((ext_vector_type(8))) short short8;
typedef __attribute__((ext_vector_type(4))) float f32x4;
typedef unsigned short ushort_t;
typedef unsigned int uint_t;

__device__ __forceinline__ float lrelu(float x) { return x > 0.f ? x : 0.1f * x; }
__device__ __forceinline__ ushort_t f2bf(float f) {
    unsigned int u = __float_as_uint(f);
    unsigned int r = u + 0x7fffu + ((u >> 16) & 1u);
    return (ushort_t)(r >> 16);
}
__device__ __forceinline__ float bf2f(ushort_t u) {
    return __uint_as_float(((uint_t)u) << 16);
}

struct MegaParams {
    const float *feat, *gamma, *beta, *mean, *var, *W1, *b1, *W2, *b2;
    const float *giW, *gia_src, *gia_dst, *guW, *gua_src, *gua_dst;
    const int *ind_mask;
    const float *head_W, *head_b, *proj_W;
    float *C, *CbI, *CbU, *H_I, *H_U, *factors, *recon, *A, *abar;
    ushort_t *hT;
    float *ssrc, *sdst, *den_p;
    ushort_t *num_p;
};

// ---- proj for 4 rows: h = Xl @ Wg (bf16 pair-packed into hT), scores ----
__device__ void proj4(const float* Xl, const float* __restrict__ Wg,
                      const float* __restrict__ a_src, const float* __restrict__ a_dst,
                      ushort_t* __restrict__ hT, float* __restrict__ ssrc,
                      float* __restrict__ sdst, int row0, int t)
{
    const int j = t & 127, rp = t >> 7;
    float p0 = 0.f, p1 = 0.f;
    for (int k = 0; k < DD; ++k) {
        float w = Wg[k * DD + j];
        p0 += Xl[(2 * rp) * DD + k] * w;
        p1 += Xl[(2 * rp + 1) * DD + k] * w;
    }
    const int gr = row0 + 2 * rp;
    const int b = gr / NN, n = gr % NN;
    uint_t pk = (uint_t)f2bf(p0) | ((uint_t)f2bf(p1) << 16);
    *(uint_t*)&hT[(b * DD + j) * HTPAD + n] = pk;

    float as = a_src[j], ad = a_dst[j];
    float ps0 = p0 * as, ps1 = p1 * as;
    float pd0 = p0 * ad, pd1 = p1 * ad;
#pragma unroll
    for (int off = 1; off <= 16; off <<= 1) {
        ps0 += __shfl_xor(ps0, off);
        ps1 += __shfl_xor(ps1, off);
        pd0 += __shfl_xor(pd0, off);
        pd1 += __shfl_xor(pd1, off);
    }
    if ((t & 31) == 0) {
        int h = (j >> 5) & 3;
        ssrc[(b * NH + h) * NN + n] = ps0 * LOG2E;
        ssrc[(b * NH + h) * NN + n + 1] = ps1 * LOG2E;
        sdst[(b * NH + h) * NN + n] = pd0 * LOG2E;
        sdst[(b * NH + h) * NN + n + 1] = pd1 * LOG2E;
    }
}

// ---- encoder (BN+MLP) + GAT1 proj, 4 rows ----
__device__ void enc_proj4(const MegaParams& P, int row0, int t, float* sm)
{
    float* xn = sm;            // [4][64]
    float* hid = sm + 256;     // [4][128]
    float* Cl = sm + 768;      // [4][128]
    {
        int row = t >> 6, m = t & 63;
        float f = P.feat[(row0 + row) * FF + m];
        xn[row * FF + m] =
            (f - P.mean[m]) * rsqrtf(P.var[m] + 1e-5f) * P.gamma[m] + P.beta[m];
    }
    __syncthreads();
    const int j = t & 127, rp = t >> 7;
    const int a0 = 2 * rp, a1 = 2 * rp + 1;
    float c0 = P.b1[j], c1 = c0;
    for (int k = 0; k < FF; ++k) {
        float w = P.W1[k * DD + j];
        c0 += xn[a0 * FF + k] * w;
        c1 += xn[a1 * FF + k] * w;
    }
    hid[a0 * DD + j] = fmaxf(c0, 0.f);
    hid[a1 * DD + j] = fmaxf(c1, 0.f);
    __syncthreads();
    c0 = P.b2[j]; c1 = c0;
    for (int k = 0; k < DD; ++k) {
        float w = P.W2[k * DD + j];
        c0 += hid[a0 * DD + k] * w;
        c1 += hid[a1 * DD + k] * w;
    }
    P.C[(row0 + a0) * DD + j] = c0;
    P.C[(row0 + a1) * DD + j] = c1;
    Cl[a0 * DD + j] = c0;
    Cl[a1 * DD + j] = c1;
    __syncthreads();
    proj4(Cl, P.giW, P.gia_src, P.gia_dst, P.hT, P.ssrc, P.sdst, row0, t);
}

// ---- factor attention, one 8-row unit ----
__device__ void fa_unit(const MegaParams& P, int u, int t, float* sm)
{
    float* fl = sm;            // [8][64]
    float* abp = sm + 512;     // [4][64]
    const int hbg = u / 250;
    const int n_base = (u % 250) * 8;
    const int h = hbg >> 1, b = hbg & 1;
    for (int idx = t; idx < 8 * FF; idx += 256)
        fl[idx] = P.feat[(b * NN + n_base + (idx >> 6)) * FF + (idx & 63)];
    __syncthreads();
    const int ns = t >> 6, k = t & 63;
    const float* Pr = P.proj_W + (h * FF + k) * FF;
    float u0 = 0.f, u1 = 0.f;
    for (int m = 0; m < FF; ++m) {
        float pv = Pr[m];
        u0 += fl[ns * FF + m] * pv;
        u1 += fl[(ns + 4) * FF + m] * pv;
    }
    u0 = lrelu(u0); u1 = lrelu(u1);
    float mx0 = u0, mx1 = u1;
#pragma unroll
    for (int off = 32; off; off >>= 1) {
        mx0 = fmaxf(mx0, __shfl_xor(mx0, off));
        mx1 = fmaxf(mx1, __shfl_xor(mx1, off));
    }
    float e0 = __expf(u0 - mx0), e1 = __expf(u1 - mx1);
    float sm0 = e0, sm1 = e1;
#pragma unroll
    for (int off = 32; off; off >>= 1) {
        sm0 += __shfl_xor(sm0, off);
        sm1 += __shfl_xor(sm1, off);
    }
    float a0 = e0 / sm0, a1 = e1 / sm1;
    P.A[((h * BB + b) * NN + n_base + ns) * FF + k] = a0;
    P.A[((h * BB + b) * NN + n_base + ns + 4) * FF + k] = a1;
    abp[ns * FF + k] = a0 + a1;
    __syncthreads();
    if (t < FF) {
        float s = abp[t] + abp[FF + t] + abp[2 * FF + t] + abp[3 * FF + t];
        atomicAdd(&P.abar[(h * BB + b) * FF + t], s);
    }
}

// ---- attn unit: 16 q-rows x 256-j segment, wave = head, MFMA ----
template <int MASKED>
__device__ void attn_unit(const int* __restrict__ mask,
                          const ushort_t* __restrict__ hT,
                          const float* __restrict__ ssrc,
                          const float* __restrict__ sdst,
                          ushort_t* __restrict__ num_p,
                          float* __restrict__ den_p,
                          int unit, int t, float* sm)
{
    float* sdl = sm;           // [NH][SEGSTRIDE]
    const int iblk = unit % 125;
    const int tmp = unit / 125;
    const int b = tmp & 1;
    const int seg = tmp >> 1;
    const int i0 = iblk * 16;
    const int jbeg = seg * SEGSTRIDE;
    const int jlim = min(NN - jbeg, SEGSTRIDE);

    const int h = t >> 6;
    const int l = t & 63;
    const int il = l & 15;
    const int g = l >> 4;

#pragma unroll
    for (int jj = l; jj < SEGSTRIDE; jj += 64)
        sdl[h * SEGSTRIDE + jj] =
            (jj < jlim) ? sdst[(b * NH + h) * NN + jbeg + jj] : -3000.f;
    __syncthreads();

    const float sS = ssrc[(b * NH + h) * NN + i0 + il];
    const int* mrow = mask + (long)b * NN * NN + (long)(i0 + il) * NN + jbeg;
    const ushort_t* hrow0 = hT + ((b * DD + 32 * h + il) * HTPAD + jbeg);
    const ushort_t* hrow1 = hrow0 + 16 * HTPAD;

    f32x4 acc0 = {0.f, 0.f, 0.f, 0.f};
    f32x4 acc1 = {0.f, 0.f, 0.f, 0.f};
    float den0 = 0.f, den1 = 0.f;

    for (int jc = 0; jc < SEGSTRIDE; jc += 32) {
        const int jloc = jc + 8 * g;
        int4 m0 = make_int4(1, 1, 1, 1), m1 = make_int4(1, 1, 1, 1);
        if (MASKED) {
            if (jloc < jlim)     m0 = *(const int4*)(mrow + jloc);
            if (jloc + 4 < jlim) m1 = *(const int4*)(mrow + jloc + 4);
        }
        float4 s0 = *(const float4*)&sdl[h * SEGSTRIDE + jloc];
        float4 s1 = *(const float4*)&sdl[h * SEGSTRIDE + jloc + 4];
        float w0, w1, w2, w3, w4, w5, w6, w7;
        {
            float x, e;
#define SCORE(SRC, MM, OUT)                                        \
            x = sS + SRC;                                          \
            x = fmaxf(x, 0.1f * x);                                \
            asm("v_exp_f32 %0, %1" : "=v"(e) : "v"(x));            \
            OUT = (!MASKED || MM) ? e : 0.f;
            SCORE(s0.x, m0.x, w0) SCORE(s0.y, m0.y, w1)
            SCORE(s0.z, m0.z, w2) SCORE(s0.w, m0.w, w3)
            SCORE(s1.x, m1.x, w4) SCORE(s1.y, m1.y, w5)
            SCORE(s1.z, m1.z, w6) SCORE(s1.w, m1.w, w7)
#undef SCORE
        }
        den0 += (w0 + w1) + (w2 + w3);
        den1 += (w4 + w5) + (w6 + w7);
        union { uint_t u[4]; short8 s8; } pk;
        asm("v_cvt_pk_bf16_f32 %0, %1, %2" : "=v"(pk.u[0]) : "v"(w0), "v"(w1));
        asm("v_cvt_pk_bf16_f32 %0, %1, %2" : "=v"(pk.u[1]) : "v"(w2), "v"(w3));
        asm("v_cvt_pk_bf16_f32 %0, %1, %2" : "=v"(pk.u[2]) : "v"(w4), "v"(w5));
        asm("v_cvt_pk_bf16_f32 %0, %1, %2" : "=v"(pk.u[3]) : "v"(w6), "v"(w7));
        short8 bf0 = *(const short8*)(hrow0 + jloc);
        short8 bf1 = *(const short8*)(hrow1 + jloc);
        acc0 = __builtin_amdgcn_mfma_f32_16x16x32_bf16(pk.s8, bf0, acc0, 0, 0, 0);
        acc1 = __builtin_amdgcn_mfma_f32_16x16x32_bf16(pk.s8, bf1, acc1, 0, 0, 0);
    }

    float den_acc = den0 + den1;
    den_acc += __shfl_xor(den_acc, 16);
    den_acc += __shfl_xor(den_acc, 32);
    if (l < 16)
        den_p[seg * DENTOT + (b * NN + i0 + l) * NH + h] = den_acc;

    const long segbase = (long)seg * SEGTOT;
#pragma unroll
    for (int r = 0; r < 4; ++r) {
        long base = segbase + ((long)b * NN + i0 + 4 * g + r) * DD + 32 * h + il;
        num_p[base] = f2bf(acc0[r]);
        num_p[base + 16] = f2bf(acc1[r]);
    }
}

// ---- finish GAT1 + GAT2 proj, 4 rows ----
__device__ void finish_proj4(const MegaParams& P, int row0, int t, float* sm)
{
    float* Xl = sm;            // [4][128]
    float* denl = sm + 512;    // [4][4]
    if (t < 16) {
        int rr = t >> 2, hh = t & 3;
        float s = 0.f;
#pragma unroll
        for (int sg = 0; sg < NSEG; ++sg)
            s += P.den_p[sg * DENTOT + (row0 + rr) * NH + hh];
        denl[rr * 4 + hh] = s;
    }
    __syncthreads();
    const int j = t & 127, rp = t >> 7;
#pragma unroll
    for (int rr = 0; rr < 2; ++rr) {
        int lr = 2 * rp + rr;
        int gr = row0 + lr;
        float s = 0.f;
#pragma unroll
        for (int sg = 0; sg < NSEG; ++sg)
            s += bf2f(P.num_p[sg * SEGTOT + gr * DD + j]);
        float inv = 1.f / denl[lr * 4 + (j >> 5)];
        float cv = P.C[gr * DD + j];
        float Hv = s * inv, cb = cv - Hv;
        P.H_I[gr * DD + j] = Hv;
        P.CbI[gr * DD + j] = cb;
        Xl[lr * DD + j] = cb;
    }
    __syncthreads();
    proj4(Xl, P.guW, P.gua_src, P.gua_dst, P.hT, P.ssrc, P.sdst, row0, t);
}

// ---- finish GAT2 + deep factor heads + recon, 4 rows ----
__device__ void finish_factors4(const MegaParams& P, int row0, int t, float* sm)
{
    float* ctx = sm;           // [4][384]
    float* denl = sm + 1536;   // [4][4]
    if (t < 16) {
        int rr = t >> 2, hh = t & 3;
        float s = 0.f;
#pragma unroll
        for (int sg = 0; sg < NSEG; ++sg)
            s += P.den_p[sg * DENTOT + (row0 + rr) * NH + hh];
        denl[rr * 4 + hh] = s;
    }
    __syncthreads();
    const int j = t & 127, rp = t >> 7;
#pragma unroll
    for (int rr = 0; rr < 2; ++rr) {
        int lr = 2 * rp + rr;
        int gr = row0 + lr;
        float s = 0.f;
#pragma unroll
        for (int sg = 0; sg < NSEG; ++sg)
            s += bf2f(P.num_p[sg * SEGTOT + gr * DD + j]);
        float inv = 1.f / denl[lr * 4 + (j >> 5)];
        float ci = P.CbI[gr * DD + j];
        float cv = P.C[gr * DD + j];
        float Hv = s * inv, cu = ci - Hv;
        P.H_U[gr * DD + j] = Hv;
        P.CbU[gr * DD + j] = cu;
        ctx[lr * DEEP + j] = cv;
        ctx[lr * DEEP + DD + j] = ci;
        ctx[lr * DEEP + 2 * DD + j] = cu;
    }
    __syncthreads();
    const int w = t >> 6, l = t & 63;
    const int gr = row0 + w;
    const int b = gr / NN;
#pragma unroll
    for (int h = 0; h < HNZ; ++h) {
        const float* hw = P.head_W + h * DEEP;
        float a = 0.f;
#pragma unroll
        for (int i = 0; i < 6; ++i)
            a += ctx[w * DEEP + l + 64 * i] * hw[l + 64 * i];
        float rc = P.feat[gr * FF + l] * P.abar[(h * BB + b) * FF + l];
#pragma unroll
        for (int off = 32; off; off >>= 1) {
            a += __shfl_xor(a, off);
            rc += __shfl_xor(rc, off);
        }
        if (l == 0) {
            P.factors[h * (BB * NN) + gr] = lrelu(a + P.head_b[h]);
            P.recon[h * (BB * NN) + gr] = rc * (1.f / NN);
        }
    }
}

// ---------------- cooperative mega-kernel (grid-stride phases) ----------------
__global__ __launch_bounds__(256, 4) void k_mega(MegaParams P)
{
    cg::grid_group grid = cg::this_grid();
    __shared__ float sm[SMSZ];
    const int blk = blockIdx.x, t = threadIdx.x;
    const int nb = gridDim.x;

    for (int u = blk; u < 1000; u += nb) {
        __syncthreads();
        enc_proj4(P, u * 4, t, sm);
    }
    for (int u = blk; u < HNZ * BB * 250; u += nb) {
        __syncthreads();
        fa_unit(P, u, t, sm);
    }
    grid.sync();

    for (int u = blk; u < NSEG * BB * 125; u += nb) {
        __syncthreads();
        attn_unit<1>(P.ind_mask, P.hT, P.ssrc, P.sdst, P.num_p, P.den_p, u, t, sm);
    }
    grid.sync();

    for (int u = blk; u < 1000; u += nb) {
        __syncthreads();
        finish_proj4(P, u * 4, t, sm);
    }
    grid.sync();

    for (int u = blk; u < NSEG * BB * 125; u += nb) {
        __syncthreads();
        attn_unit<0>(P.ind_mask, P.hT, P.ssrc, P.sdst, P.num_p, P.den_p, u, t, sm);
    }
    grid.sync();

    for (int u = blk; u < 1000; u += nb) {
        __syncthreads();
        finish_factors4(P, u * 4, t, sm);
    }
}

// ---------------- fallback wrappers (plain kernels) ----------------
__global__ __launch_bounds__(256) void k_encproj_w(MegaParams P) {
    __shared__ float sm[SMSZ];
    enc_proj4(P, blockIdx.x * 4, threadIdx.x, sm);
}
__global__ __launch_bounds__(256) void k_fa_w(MegaParams P) {
    __shared__ float sm[SMSZ];
    fa_unit(P, blockIdx.x, threadIdx.x, sm);
}
template <int MASKED>
__global__ __launch_bounds__(256) void k_attn_w(MegaParams P) {
    __shared__ float sm[SMSZ];
    attn_unit<MASKED>(P.ind_mask, P.hT, P.ssrc, P.sdst, P.num_p, P.den_p,
                      blockIdx.x, threadIdx.x, sm);
}
__global__ __launch_bounds__(256) void k_finishproj_w(MegaParams P) {
    __shared__ float sm[SMSZ];
    finish_proj4(P, blockIdx.x * 4, threadIdx.x, sm);
}
__global__ __launch_bounds__(256) void k_finishfactors_w(MegaParams P) {
    __shared__ float sm[SMSZ];
    finish_factors4(P, blockIdx.x * 4, threadIdx.x, sm);
}

extern "C" void kernel_launch(void* const* d_in, const int* in_sizes, int n_in,
                              void* d_out, int out_size, void* d_ws, size_t ws_size,
                              hipStream_t stream)
{
    float* out = (float*)d_out;
    float* ws = (float*)d_ws;

    MegaParams P;
    P.feat     = (const float*)d_in[0];
    P.ind_mask = (const int*)d_in[1];
    P.gamma    = (const float*)d_in[3];
    P.beta     = (const float*)d_in[4];
    P.mean     = (const float*)d_in[5];
    P.var      = (const float*)d_in[6];
    P.W1 = (const float*)d_in[7];
    P.b1 = (const float*)d_in[8];
    P.W2 = (const float*)d_in[9];
    P.b2 = (const float*)d_in[10];
    P.giW = (const float*)d_in[11];
    P.gia_src = (const float*)d_in[12];
    P.gia_dst = (const float*)d_in[13];
    P.guW = (const float*)d_in[14];
    P.gua_src = (const float*)d_in[15];
    P.gua_dst = (const float*)d_in[16];
    P.head_W = (const float*)d_in[17];
    P.head_b = (const float*)d_in[18];
    P.proj_W = (const float*)d_in[19];

    P.C       = out;
    P.CbI     = out + 512000;
    P.CbU     = out + 1024000;
    P.H_I     = out + 1536000;
    P.H_U     = out + 2048000;
    P.factors = out + 2560000;
    P.recon   = out + 2572000;
    P.A       = out + 2584000;

    P.hT    = (ushort_t*)ws;
    P.ssrc  = ws + 262400;
    P.sdst  = ws + 278400;
    P.den_p = ws + 294400;
    P.num_p = (ushort_t*)(ws + 422400);
    P.abar  = ws + 2470400;

    hipMemsetAsync(P.abar, 0, HNZ * BB * FF * sizeof(float), stream);

    int occ = 0;
    hipError_t oe = hipOccupancyMaxActiveBlocksPerMultiprocessor(&occ, k_mega, 256, 0);
    bool coop_ok = (oe == hipSuccess && occ >= 1);
    if (coop_ok) {
        int nb = occ * 256;               // 256 CUs on MI355X
        if (nb > 1024) nb = 1024;
        void* args[] = { &P };
        hipError_t le = hipLaunchCooperativeKernel((const void*)k_mega, dim3(nb),
                                                   dim3(256), args, 0, stream);
        coop_ok = (le == hipSuccess);
    }
    if (!coop_ok) {
        k_fa_w<<<HNZ * BB * 250, 256, 0, stream>>>(P);
        k_encproj_w<<<1000, 256, 0, stream>>>(P);
        k_attn_w<1><<<NSEG * BB * 125, 256, 0, stream>>>(P);
        k_finishproj_w<<<1000, 256, 0, stream>>>(P);
        k_attn_w<0><<<NSEG * BB * 125, 256, 0, stream>>>(P);
        k_finishfactors_w<<<1000, 256, 0, stream>>>(P);
    }
}

// Round 12
// 232.836 us; speedup vs baseline: 2.6692x; 2.6692x over previous
//
#include <hip/hip_runtime.h>

#define BB 2
#define NN 2000
#define FF 64
#define DD 128
#define NH 4
#define HNZ 3
#define DEEP 384
#define NSEG 8
#define SEGSTRIDE 256
#define HTPAD 2048
#define SEGTOT (BB * NN * DD)
#define DENTOT (BB * NN * NH)
#define LOG2E 1.44269504f
#define SMSZ 1600

typedef __attribute__((ext_vector_type(8))) short short8;
typedef __attribute__((ext_vector_type(4))) float f32x4;
typedef unsigned short ushort_t;
typedef unsigned int uint_t;

__device__ __forceinline__ float lrelu(float x) { return x > 0.f ? x : 0.1f * x; }
__device__ __forceinline__ ushort_t f2bf(float f) {
    unsigned int u = __float_as_uint(f);
    unsigned int r = u + 0x7fffu + ((u >> 16) & 1u);
    return (ushort_t)(r >> 16);
}
__device__ __forceinline__ float bf2f(ushort_t u) {
    return __uint_as_float(((uint_t)u) << 16);
}

struct MegaParams {
    const float *feat, *gamma, *beta, *mean, *var, *W1, *b1, *W2, *b2;
    const float *giW, *gia_src, *gia_dst, *guW, *gua_src, *gua_dst;
    const int *ind_mask;
    const float *head_W, *head_b, *proj_W;
    float *C, *CbI, *CbU, *H_I, *H_U, *factors, *recon, *A, *abar;
    ushort_t *hT;
    float *ssrc, *sdst, *den_p;
    ushort_t *num_p;
};

// ---- proj for 4 rows: h = Xl @ Wg (bf16 pair-packed into hT), scores ----
__device__ void proj4(const float* Xl, const float* __restrict__ Wg,
                      const float* __restrict__ a_src, const float* __restrict__ a_dst,
                      ushort_t* __restrict__ hT, float* __restrict__ ssrc,
                      float* __restrict__ sdst, int row0, int t)
{
    const int j = t & 127, rp = t >> 7;
    float p0 = 0.f, p1 = 0.f;
    for (int k = 0; k < DD; ++k) {
        float w = Wg[k * DD + j];
        p0 += Xl[(2 * rp) * DD + k] * w;
        p1 += Xl[(2 * rp + 1) * DD + k] * w;
    }
    const int gr = row0 + 2 * rp;
    const int b = gr / NN, n = gr % NN;
    uint_t pk = (uint_t)f2bf(p0) | ((uint_t)f2bf(p1) << 16);
    *(uint_t*)&hT[(b * DD + j) * HTPAD + n] = pk;

    float as = a_src[j], ad = a_dst[j];
    float ps0 = p0 * as, ps1 = p1 * as;
    float pd0 = p0 * ad, pd1 = p1 * ad;
#pragma unroll
    for (int off = 1; off <= 16; off <<= 1) {
        ps0 += __shfl_xor(ps0, off);
        ps1 += __shfl_xor(ps1, off);
        pd0 += __shfl_xor(pd0, off);
        pd1 += __shfl_xor(pd1, off);
    }
    if ((t & 31) == 0) {
        int h = (j >> 5) & 3;
        ssrc[(b * NH + h) * NN + n] = ps0 * LOG2E;
        ssrc[(b * NH + h) * NN + n + 1] = ps1 * LOG2E;
        sdst[(b * NH + h) * NN + n] = pd0 * LOG2E;
        sdst[(b * NH + h) * NN + n + 1] = pd1 * LOG2E;
    }
}

// ---- encoder (BN+MLP) + GAT1 proj, 4 rows ----
__device__ void enc_proj4(const MegaParams& P, int row0, int t, float* sm)
{
    float* xn = sm;            // [4][64]
    float* hid = sm + 256;     // [4][128]
    float* Cl = sm + 768;      // [4][128]
    {
        int row = t >> 6, m = t & 63;
        float f = P.feat[(row0 + row) * FF + m];
        xn[row * FF + m] =
            (f - P.mean[m]) * rsqrtf(P.var[m] + 1e-5f) * P.gamma[m] + P.beta[m];
    }
    __syncthreads();
    const int j = t & 127, rp = t >> 7;
    const int a0 = 2 * rp, a1 = 2 * rp + 1;
    float c0 = P.b1[j], c1 = c0;
    for (int k = 0; k < FF; ++k) {
        float w = P.W1[k * DD + j];
        c0 += xn[a0 * FF + k] * w;
        c1 += xn[a1 * FF + k] * w;
    }
    hid[a0 * DD + j] = fmaxf(c0, 0.f);
    hid[a1 * DD + j] = fmaxf(c1, 0.f);
    __syncthreads();
    c0 = P.b2[j]; c1 = c0;
    for (int k = 0; k < DD; ++k) {
        float w = P.W2[k * DD + j];
        c0 += hid[a0 * DD + k] * w;
        c1 += hid[a1 * DD + k] * w;
    }
    P.C[(row0 + a0) * DD + j] = c0;
    P.C[(row0 + a1) * DD + j] = c1;
    Cl[a0 * DD + j] = c0;
    Cl[a1 * DD + j] = c1;
    __syncthreads();
    proj4(Cl, P.giW, P.gia_src, P.gia_dst, P.hT, P.ssrc, P.sdst, row0, t);
}

// ---- factor attention, one 8-row unit ----
__device__ void fa_unit(const MegaParams& P, int u, int t, float* sm)
{
    float* fl = sm;            // [8][64]
    float* abp = sm + 512;     // [4][64]
    const int hbg = u / 250;
    const int n_base = (u % 250) * 8;
    const int h = hbg >> 1, b = hbg & 1;
    for (int idx = t; idx < 8 * FF; idx += 256)
        fl[idx] = P.feat[(b * NN + n_base + (idx >> 6)) * FF + (idx & 63)];
    __syncthreads();
    const int ns = t >> 6, k = t & 63;
    const float* Pr = P.proj_W + (h * FF + k) * FF;
    float u0 = 0.f, u1 = 0.f;
    for (int m = 0; m < FF; ++m) {
        float pv = Pr[m];
        u0 += fl[ns * FF + m] * pv;
        u1 += fl[(ns + 4) * FF + m] * pv;
    }
    u0 = lrelu(u0); u1 = lrelu(u1);
    float mx0 = u0, mx1 = u1;
#pragma unroll
    for (int off = 32; off; off >>= 1) {
        mx0 = fmaxf(mx0, __shfl_xor(mx0, off));
        mx1 = fmaxf(mx1, __shfl_xor(mx1, off));
    }
    float e0 = __expf(u0 - mx0), e1 = __expf(u1 - mx1);
    float sm0 = e0, sm1 = e1;
#pragma unroll
    for (int off = 32; off; off >>= 1) {
        sm0 += __shfl_xor(sm0, off);
        sm1 += __shfl_xor(sm1, off);
    }
    float a0 = e0 / sm0, a1 = e1 / sm1;
    P.A[((h * BB + b) * NN + n_base + ns) * FF + k] = a0;
    P.A[((h * BB + b) * NN + n_base + ns + 4) * FF + k] = a1;
    abp[ns * FF + k] = a0 + a1;
    __syncthreads();
    if (t < FF) {
        float s = abp[t] + abp[FF + t] + abp[2 * FF + t] + abp[3 * FF + t];
        atomicAdd(&P.abar[(h * BB + b) * FF + t], s);
    }
}

// ---- attn unit: 16 q-rows x 256-j segment, wave = head, MFMA ----
template <int MASKED>
__device__ void attn_unit(const int* __restrict__ mask,
                          const ushort_t* __restrict__ hT,
                          const float* __restrict__ ssrc,
                          const float* __restrict__ sdst,
                          ushort_t* __restrict__ num_p,
                          float* __restrict__ den_p,
                          int unit, int t, float* sm)
{
    float* sdl = sm;           // [NH][SEGSTRIDE]
    const int iblk = unit % 125;
    const int tmp = unit / 125;
    const int b = tmp & 1;
    const int seg = tmp >> 1;
    const int i0 = iblk * 16;
    const int jbeg = seg * SEGSTRIDE;
    const int jlim = min(NN - jbeg, SEGSTRIDE);

    const int h = t >> 6;
    const int l = t & 63;
    const int il = l & 15;
    const int g = l >> 4;

#pragma unroll
    for (int jj = l; jj < SEGSTRIDE; jj += 64)
        sdl[h * SEGSTRIDE + jj] =
            (jj < jlim) ? sdst[(b * NH + h) * NN + jbeg + jj] : -3000.f;
    __syncthreads();

    const float sS = ssrc[(b * NH + h) * NN + i0 + il];
    const int* mrow = mask + (long)b * NN * NN + (long)(i0 + il) * NN + jbeg;
    const ushort_t* hrow0 = hT + ((b * DD + 32 * h + il) * HTPAD + jbeg);
    const ushort_t* hrow1 = hrow0 + 16 * HTPAD;

    f32x4 acc0 = {0.f, 0.f, 0.f, 0.f};
    f32x4 acc1 = {0.f, 0.f, 0.f, 0.f};
    float den0 = 0.f, den1 = 0.f;

    for (int jc = 0; jc < SEGSTRIDE; jc += 32) {
        const int jloc = jc + 8 * g;
        int4 m0 = make_int4(1, 1, 1, 1), m1 = make_int4(1, 1, 1, 1);
        if (MASKED) {
            if (jloc < jlim)     m0 = *(const int4*)(mrow + jloc);
            if (jloc + 4 < jlim) m1 = *(const int4*)(mrow + jloc + 4);
        }
        float4 s0 = *(const float4*)&sdl[h * SEGSTRIDE + jloc];
        float4 s1 = *(const float4*)&sdl[h * SEGSTRIDE + jloc + 4];
        float w0, w1, w2, w3, w4, w5, w6, w7;
        {
            float x, e;
#define SCORE(SRC, MM, OUT)                                        \
            x = sS + SRC;                                          \
            x = fmaxf(x, 0.1f * x);                                \
            asm("v_exp_f32 %0, %1" : "=v"(e) : "v"(x));            \
            OUT = (!MASKED || MM) ? e : 0.f;
            SCORE(s0.x, m0.x, w0) SCORE(s0.y, m0.y, w1)
            SCORE(s0.z, m0.z, w2) SCORE(s0.w, m0.w, w3)
            SCORE(s1.x, m1.x, w4) SCORE(s1.y, m1.y, w5)
            SCORE(s1.z, m1.z, w6) SCORE(s1.w, m1.w, w7)
#undef SCORE
        }
        den0 += (w0 + w1) + (w2 + w3);
        den1 += (w4 + w5) + (w6 + w7);
        union { uint_t u[4]; short8 s8; } pk;
        asm("v_cvt_pk_bf16_f32 %0, %1, %2" : "=v"(pk.u[0]) : "v"(w0), "v"(w1));
        asm("v_cvt_pk_bf16_f32 %0, %1, %2" : "=v"(pk.u[1]) : "v"(w2), "v"(w3));
        asm("v_cvt_pk_bf16_f32 %0, %1, %2" : "=v"(pk.u[2]) : "v"(w4), "v"(w5));
        asm("v_cvt_pk_bf16_f32 %0, %1, %2" : "=v"(pk.u[3]) : "v"(w6), "v"(w7));
        short8 bf0 = *(const short8*)(hrow0 + jloc);
        short8 bf1 = *(const short8*)(hrow1 + jloc);
        acc0 = __builtin_amdgcn_mfma_f32_16x16x32_bf16(pk.s8, bf0, acc0, 0, 0, 0);
        acc1 = __builtin_amdgcn_mfma_f32_16x16x32_bf16(pk.s8, bf1, acc1, 0, 0, 0);
    }

    float den_acc = den0 + den1;
    den_acc += __shfl_xor(den_acc, 16);
    den_acc += __shfl_xor(den_acc, 32);
    if (l < 16)
        den_p[seg * DENTOT + (b * NN + i0 + l) * NH + h] = den_acc;

    const long segbase = (long)seg * SEGTOT;
#pragma unroll
    for (int r = 0; r < 4; ++r) {
        long base = segbase + ((long)b * NN + i0 + 4 * g + r) * DD + 32 * h + il;
        num_p[base] = f2bf(acc0[r]);
        num_p[base + 16] = f2bf(acc1[r]);
    }
}

// ---- finish GAT1 + GAT2 proj, 4 rows ----
__device__ void finish_proj4(const MegaParams& P, int row0, int t, float* sm)
{
    float* Xl = sm;            // [4][128]
    float* denl = sm + 512;    // [4][4]
    if (t < 16) {
        int rr = t >> 2, hh = t & 3;
        float s = 0.f;
#pragma unroll
        for (int sg = 0; sg < NSEG; ++sg)
            s += P.den_p[sg * DENTOT + (row0 + rr) * NH + hh];
        denl[rr * 4 + hh] = s;
    }
    __syncthreads();
    const int j = t & 127, rp = t >> 7;
#pragma unroll
    for (int rr = 0; rr < 2; ++rr) {
        int lr = 2 * rp + rr;
        int gr = row0 + lr;
        float s = 0.f;
#pragma unroll
        for (int sg = 0; sg < NSEG; ++sg)
            s += bf2f(P.num_p[sg * SEGTOT + gr * DD + j]);
        float inv = 1.f / denl[lr * 4 + (j >> 5)];
        float cv = P.C[gr * DD + j];
        float Hv = s * inv, cb = cv - Hv;
        P.H_I[gr * DD + j] = Hv;
        P.CbI[gr * DD + j] = cb;
        Xl[lr * DD + j] = cb;
    }
    __syncthreads();
    proj4(Xl, P.guW, P.gua_src, P.gua_dst, P.hT, P.ssrc, P.sdst, row0, t);
}

// ---- finish GAT2 + deep factor heads + recon, 4 rows ----
__device__ void finish_factors4(const MegaParams& P, int row0, int t, float* sm)
{
    float* ctx = sm;           // [4][384]
    float* denl = sm + 1536;   // [4][4]
    if (t < 16) {
        int rr = t >> 2, hh = t & 3;
        float s = 0.f;
#pragma unroll
        for (int sg = 0; sg < NSEG; ++sg)
            s += P.den_p[sg * DENTOT + (row0 + rr) * NH + hh];
        denl[rr * 4 + hh] = s;
    }
    __syncthreads();
    const int j = t & 127, rp = t >> 7;
#pragma unroll
    for (int rr = 0; rr < 2; ++rr) {
        int lr = 2 * rp + rr;
        int gr = row0 + lr;
        float s = 0.f;
#pragma unroll
        for (int sg = 0; sg < NSEG; ++sg)
            s += bf2f(P.num_p[sg * SEGTOT + gr * DD + j]);
        float inv = 1.f / denl[lr * 4 + (j >> 5)];
        float ci = P.CbI[gr * DD + j];
        float cv = P.C[gr * DD + j];
        float Hv = s * inv, cu = ci - Hv;
        P.H_U[gr * DD + j] = Hv;
        P.CbU[gr * DD + j] = cu;
        ctx[lr * DEEP + j] = cv;
        ctx[lr * DEEP + DD + j] = ci;
        ctx[lr * DEEP + 2 * DD + j] = cu;
    }
    __syncthreads();
    const int w = t >> 6, l = t & 63;
    const int gr = row0 + w;
    const int b = gr / NN;
#pragma unroll
    for (int h = 0; h < HNZ; ++h) {
        const float* hw = P.head_W + h * DEEP;
        float a = 0.f;
#pragma unroll
        for (int i = 0; i < 6; ++i)
            a += ctx[w * DEEP + l + 64 * i] * hw[l + 64 * i];
        float rc = P.feat[gr * FF + l] * P.abar[(h * BB + b) * FF + l];
#pragma unroll
        for (int off = 32; off; off >>= 1) {
            a += __shfl_xor(a, off);
            rc += __shfl_xor(rc, off);
        }
        if (l == 0) {
            P.factors[h * (BB * NN) + gr] = lrelu(a + P.head_b[h]);
            P.recon[h * (BB * NN) + gr] = rc * (1.f / NN);
        }
    }
}

// ---------------- plain kernels ----------------
__global__ __launch_bounds__(256) void k_encproj_w(MegaParams P) {
    __shared__ float sm[SMSZ];
    enc_proj4(P, blockIdx.x * 4, threadIdx.x, sm);
}
__global__ __launch_bounds__(256) void k_fa_w(MegaParams P) {
    __shared__ float sm[SMSZ];
    fa_unit(P, blockIdx.x, threadIdx.x, sm);
}
template <int MASKED>
__global__ __launch_bounds__(256) void k_attn_w(MegaParams P) {
    __shared__ float sm[SMSZ];
    attn_unit<MASKED>(P.ind_mask, P.hT, P.ssrc, P.sdst, P.num_p, P.den_p,
                      blockIdx.x, threadIdx.x, sm);
}
__global__ __launch_bounds__(256) void k_finishproj_w(MegaParams P) {
    __shared__ float sm[SMSZ];
    finish_proj4(P, blockIdx.x * 4, threadIdx.x, sm);
}
__global__ __launch_bounds__(256) void k_finishfactors_w(MegaParams P) {
    __shared__ float sm[SMSZ];
    finish_factors4(P, blockIdx.x * 4, threadIdx.x, sm);
}

extern "C" void kernel_launch(void* const* d_in, const int* in_sizes, int n_in,
                              void* d_out, int out_size, void* d_ws, size_t ws_size,
                              hipStream_t stream)
{
    float* out = (float*)d_out;
    float* ws = (float*)d_ws;

    MegaParams P;
    P.feat     = (const float*)d_in[0];
    P.ind_mask = (const int*)d_in[1];
    P.gamma    = (const float*)d_in[3];
    P.beta     = (const float*)d_in[4];
    P.mean     = (const float*)d_in[5];
    P.var      = (const float*)d_in[6];
    P.W1 = (const float*)d_in[7];
    P.b1 = (const float*)d_in[8];
    P.W2 = (const float*)d_in[9];
    P.b2 = (const float*)d_in[10];
    P.giW = (const float*)d_in[11];
    P.gia_src = (const float*)d_in[12];
    P.gia_dst = (const float*)d_in[13];
    P.guW = (const float*)d_in[14];
    P.gua_src = (const float*)d_in[15];
    P.gua_dst = (const float*)d_in[16];
    P.head_W = (const float*)d_in[17];
    P.head_b = (const float*)d_in[18];
    P.proj_W = (const float*)d_in[19];

    P.C       = out;
    P.CbI     = out + 512000;
    P.CbU     = out + 1024000;
    P.H_I     = out + 1536000;
    P.H_U     = out + 2048000;
    P.factors = out + 2560000;
    P.recon   = out + 2572000;
    P.A       = out + 2584000;

    P.hT    = (ushort_t*)ws;
    P.ssrc  = ws + 262400;
    P.sdst  = ws + 278400;
    P.den_p = ws + 294400;
    P.num_p = (ushort_t*)(ws + 422400);
    P.abar  = ws + 2470400;

    hipMemsetAsync(P.abar, 0, HNZ * BB * FF * sizeof(float), stream);

    k_fa_w<<<HNZ * BB * 250, 256, 0, stream>>>(P);
    k_encproj_w<<<1000, 256, 0, stream>>>(P);
    k_attn_w<1><<<NSEG * BB * 125, 256, 0, stream>>>(P);
    k_finishproj_w<<<1000, 256, 0, stream>>>(P);
    k_attn_w<0><<<NSEG * BB * 125, 256, 0, stream>>>(P);
    k_finishfactors_w<<<1000, 256, 0, stream>>>(P);
}

// Round 14
// 232.413 us; speedup vs baseline: 2.6740x; 1.0018x over previous
//
#include <hip/hip_runtime.h>

#define BB 2
#define NN 2000
#define FF 64
#define DD 128
#define NH 4
#define HNZ 3
#define DEEP 384
#define NSEG 8
#define SEGSTRIDE 256
#define HTPAD 2048
#define SEGTOT (BB * NN * DD)
#define DENTOT (BB * NN * NH)
#define LOG2E 1.44269504f
#define SMSZ 1600

typedef __attribute__((ext_vector_type(8))) short short8;
typedef __attribute__((ext_vector_type(4))) float f32x4;
typedef unsigned short ushort_t;
typedef unsigned int uint_t;

__device__ __forceinline__ float lrelu(float x) { return x > 0.f ? x : 0.1f * x; }
__device__ __forceinline__ ushort_t f2bf(float f) {
    unsigned int u = __float_as_uint(f);
    unsigned int r = u + 0x7fffu + ((u >> 16) & 1u);
    return (ushort_t)(r >> 16);
}
__device__ __forceinline__ float bf2f(ushort_t u) {
    return __uint_as_float(((uint_t)u) << 16);
}

struct MegaParams {
    const float *feat, *gamma, *beta, *mean, *var, *W1, *b1, *W2, *b2;
    const float *giW, *gia_src, *gia_dst, *guW, *gua_src, *gua_dst;
    const int *ind_mask;
    const float *head_W, *head_b, *proj_W;
    float *C, *CbI, *CbU, *H_I, *H_U, *factors, *recon, *A, *abar;
    ushort_t *hT;
    float *ssrc, *sdst, *den_p;
    ushort_t *num_p;
};

// ---- proj for 4 rows: h = Xl @ Wg (bf16 pair-packed into hT), scores ----
__device__ void proj4(const float* Xl, const float* __restrict__ Wg,
                      const float* __restrict__ a_src, const float* __restrict__ a_dst,
                      ushort_t* __restrict__ hT, float* __restrict__ ssrc,
                      float* __restrict__ sdst, int row0, int t)
{
    const int j = t & 127, rp = t >> 7;
    float p0 = 0.f, p1 = 0.f;
    for (int k = 0; k < DD; ++k) {
        float w = Wg[k * DD + j];
        p0 += Xl[(2 * rp) * DD + k] * w;
        p1 += Xl[(2 * rp + 1) * DD + k] * w;
    }
    const int gr = row0 + 2 * rp;
    const int b = gr / NN, n = gr % NN;
    uint_t pk = (uint_t)f2bf(p0) | ((uint_t)f2bf(p1) << 16);
    *(uint_t*)&hT[(b * DD + j) * HTPAD + n] = pk;

    float as = a_src[j], ad = a_dst[j];
    float ps0 = p0 * as, ps1 = p1 * as;
    float pd0 = p0 * ad, pd1 = p1 * ad;
#pragma unroll
    for (int off = 1; off <= 16; off <<= 1) {
        ps0 += __shfl_xor(ps0, off);
        ps1 += __shfl_xor(ps1, off);
        pd0 += __shfl_xor(pd0, off);
        pd1 += __shfl_xor(pd1, off);
    }
    if ((t & 31) == 0) {
        int h = (j >> 5) & 3;
        ssrc[(b * NH + h) * NN + n] = ps0 * LOG2E;
        ssrc[(b * NH + h) * NN + n + 1] = ps1 * LOG2E;
        sdst[(b * NH + h) * NN + n] = pd0 * LOG2E;
        sdst[(b * NH + h) * NN + n + 1] = pd1 * LOG2E;
    }
}

// ---- encoder (BN+MLP) + GAT1 proj, 4 rows ----
__device__ void enc_proj4(const MegaParams& P, int row0, int t, float* sm)
{
    float* xn = sm;            // [4][64]
    float* hid = sm + 256;     // [4][128]
    float* Cl = sm + 768;      // [4][128]
    {
        int row = t >> 6, m = t & 63;
        float f = P.feat[(row0 + row) * FF + m];
        xn[row * FF + m] =
            (f - P.mean[m]) * rsqrtf(P.var[m] + 1e-5f) * P.gamma[m] + P.beta[m];
    }
    __syncthreads();
    const int j = t & 127, rp = t >> 7;
    const int a0 = 2 * rp, a1 = 2 * rp + 1;
    float c0 = P.b1[j], c1 = c0;
    for (int k = 0; k < FF; ++k) {
        float w = P.W1[k * DD + j];
        c0 += xn[a0 * FF + k] * w;
        c1 += xn[a1 * FF + k] * w;
    }
    hid[a0 * DD + j] = fmaxf(c0, 0.f);
    hid[a1 * DD + j] = fmaxf(c1, 0.f);
    __syncthreads();
    c0 = P.b2[j]; c1 = c0;
    for (int k = 0; k < DD; ++k) {
        float w = P.W2[k * DD + j];
        c0 += hid[a0 * DD + k] * w;
        c1 += hid[a1 * DD + k] * w;
    }
    P.C[(row0 + a0) * DD + j] = c0;
    P.C[(row0 + a1) * DD + j] = c1;
    Cl[a0 * DD + j] = c0;
    Cl[a1 * DD + j] = c1;
    __syncthreads();
    proj4(Cl, P.giW, P.gia_src, P.gia_dst, P.hT, P.ssrc, P.sdst, row0, t);
}

// ---- factor attention, one 8-row unit ----
__device__ void fa_unit(const MegaParams& P, int u, int t, float* sm)
{
    float* fl = sm;            // [8][64]
    float* abp = sm + 512;     // [4][64]
    const int hbg = u / 250;
    const int n_base = (u % 250) * 8;
    const int h = hbg >> 1, b = hbg & 1;
    for (int idx = t; idx < 8 * FF; idx += 256)
        fl[idx] = P.feat[(b * NN + n_base + (idx >> 6)) * FF + (idx & 63)];
    __syncthreads();
    const int ns = t >> 6, k = t & 63;
    const float* Pr = P.proj_W + (h * FF + k) * FF;
    float u0 = 0.f, u1 = 0.f;
    for (int m = 0; m < FF; ++m) {
        float pv = Pr[m];
        u0 += fl[ns * FF + m] * pv;
        u1 += fl[(ns + 4) * FF + m] * pv;
    }
    u0 = lrelu(u0); u1 = lrelu(u1);
    float mx0 = u0, mx1 = u1;
#pragma unroll
    for (int off = 32; off; off >>= 1) {
        mx0 = fmaxf(mx0, __shfl_xor(mx0, off));
        mx1 = fmaxf(mx1, __shfl_xor(mx1, off));
    }
    float e0 = __expf(u0 - mx0), e1 = __expf(u1 - mx1);
    float sm0 = e0, sm1 = e1;
#pragma unroll
    for (int off = 32; off; off >>= 1) {
        sm0 += __shfl_xor(sm0, off);
        sm1 += __shfl_xor(sm1, off);
    }
    float a0 = e0 / sm0, a1 = e1 / sm1;
    P.A[((h * BB + b) * NN + n_base + ns) * FF + k] = a0;
    P.A[((h * BB + b) * NN + n_base + ns + 4) * FF + k] = a1;
    abp[ns * FF + k] = a0 + a1;
    __syncthreads();
    if (t < FF) {
        float s = abp[t] + abp[FF + t] + abp[2 * FF + t] + abp[3 * FF + t];
        atomicAdd(&P.abar[(h * BB + b) * FF + t], s);
    }
}

// ---- attn body: 16 q-rows x 256-j segment, wave = head, MFMA ----
// FULL=1: segment entirely in-bounds (segs 0..6) -> all guards constant-fold,
// loads are straight-line and batchable. FULL=0: R12-verbatim guarded path.
template <int MASKED, int FULL>
__device__ void attn_body(const int* __restrict__ mask,
                          const ushort_t* __restrict__ hT,
                          const float* __restrict__ ssrc,
                          const float* __restrict__ sdst,
                          ushort_t* __restrict__ num_p,
                          float* __restrict__ den_p,
                          int b, int seg, int i0, int t, float* sm)
{
    float* sdl = sm;           // [NH][SEGSTRIDE]
    const int jbeg = seg * SEGSTRIDE;
    const int jlim = FULL ? SEGSTRIDE : (NN - jbeg);

    const int h = t >> 6;
    const int l = t & 63;
    const int il = l & 15;
    const int g = l >> 4;

#pragma unroll
    for (int jj0 = 0; jj0 < SEGSTRIDE; jj0 += 64) {
        int jj = jj0 + l;
        sdl[h * SEGSTRIDE + jj] =
            (jj < jlim) ? sdst[(b * NH + h) * NN + jbeg + jj] : -3000.f;
    }
    __syncthreads();

    const float sS = ssrc[(b * NH + h) * NN + i0 + il];
    const int* mrow = mask + (long)b * NN * NN + (long)(i0 + il) * NN + jbeg;
    const ushort_t* hrow0 = hT + ((b * DD + 32 * h + il) * HTPAD + jbeg);
    const ushort_t* hrow1 = hrow0 + 16 * HTPAD;

    f32x4 acc0 = {0.f, 0.f, 0.f, 0.f};
    f32x4 acc1 = {0.f, 0.f, 0.f, 0.f};
    float den0 = 0.f, den1 = 0.f;

#pragma unroll
    for (int jc = 0; jc < SEGSTRIDE; jc += 32) {
        const int jloc = jc + 8 * g;
        int4 m0 = make_int4(1, 1, 1, 1), m1 = make_int4(1, 1, 1, 1);
        if (MASKED) {
            if (FULL || jloc < jlim)     m0 = *(const int4*)(mrow + jloc);
            if (FULL || jloc + 4 < jlim) m1 = *(const int4*)(mrow + jloc + 4);
        }
        float4 s0 = *(const float4*)&sdl[h * SEGSTRIDE + jloc];
        float4 s1 = *(const float4*)&sdl[h * SEGSTRIDE + jloc + 4];
        float w0, w1, w2, w3, w4, w5, w6, w7;
        {
            float x, e;
#define SCORE(SRC, MM, OUT)                                        \
            x = sS + SRC;                                          \
            x = fmaxf(x, 0.1f * x);                                \
            asm("v_exp_f32 %0, %1" : "=v"(e) : "v"(x));            \
            OUT = (!MASKED || MM) ? e : 0.f;
            SCORE(s0.x, m0.x, w0) SCORE(s0.y, m0.y, w1)
            SCORE(s0.z, m0.z, w2) SCORE(s0.w, m0.w, w3)
            SCORE(s1.x, m1.x, w4) SCORE(s1.y, m1.y, w5)
            SCORE(s1.z, m1.z, w6) SCORE(s1.w, m1.w, w7)
#undef SCORE
        }
        den0 += (w0 + w1) + (w2 + w3);
        den1 += (w4 + w5) + (w6 + w7);
        union { uint_t u[4]; short8 s8; } pk;
        asm("v_cvt_pk_bf16_f32 %0, %1, %2" : "=v"(pk.u[0]) : "v"(w0), "v"(w1));
        asm("v_cvt_pk_bf16_f32 %0, %1, %2" : "=v"(pk.u[1]) : "v"(w2), "v"(w3));
        asm("v_cvt_pk_bf16_f32 %0, %1, %2" : "=v"(pk.u[2]) : "v"(w4), "v"(w5));
        asm("v_cvt_pk_bf16_f32 %0, %1, %2" : "=v"(pk.u[3]) : "v"(w6), "v"(w7));
        short8 bf0 = *(const short8*)(hrow0 + jloc);
        short8 bf1 = *(const short8*)(hrow1 + jloc);
        acc0 = __builtin_amdgcn_mfma_f32_16x16x32_bf16(pk.s8, bf0, acc0, 0, 0, 0);
        acc1 = __builtin_amdgcn_mfma_f32_16x16x32_bf16(pk.s8, bf1, acc1, 0, 0, 0);
    }

    float den_acc = den0 + den1;
    den_acc += __shfl_xor(den_acc, 16);
    den_acc += __shfl_xor(den_acc, 32);
    if (l < 16)
        den_p[seg * DENTOT + (b * NN + i0 + l) * NH + h] = den_acc;

    const long segbase = (long)seg * SEGTOT;
#pragma unroll
    for (int r = 0; r < 4; ++r) {
        long base = segbase + ((long)b * NN + i0 + 4 * g + r) * DD + 32 * h + il;
        num_p[base] = f2bf(acc0[r]);
        num_p[base + 16] = f2bf(acc1[r]);
    }
}

template <int MASKED>
__device__ void attn_unit(const int* __restrict__ mask,
                          const ushort_t* __restrict__ hT,
                          const float* __restrict__ ssrc,
                          const float* __restrict__ sdst,
                          ushort_t* __restrict__ num_p,
                          float* __restrict__ den_p,
                          int unit, int t, float* sm)
{
    const int iblk = unit % 125;
    const int tmp = unit / 125;
    const int b = tmp & 1;
    const int seg = tmp >> 1;
    const int i0 = iblk * 16;
    if (seg * SEGSTRIDE + SEGSTRIDE <= NN)
        attn_body<MASKED, 1>(mask, hT, ssrc, sdst, num_p, den_p, b, seg, i0, t, sm);
    else
        attn_body<MASKED, 0>(mask, hT, ssrc, sdst, num_p, den_p, b, seg, i0, t, sm);
}

// ---- finish GAT1 + GAT2 proj, 4 rows ----
__device__ void finish_proj4(const MegaParams& P, int row0, int t, float* sm)
{
    float* Xl = sm;            // [4][128]
    float* denl = sm + 512;    // [4][4]
    if (t < 16) {
        int rr = t >> 2, hh = t & 3;
        float s = 0.f;
#pragma unroll
        for (int sg = 0; sg < NSEG; ++sg)
            s += P.den_p[sg * DENTOT + (row0 + rr) * NH + hh];
        denl[rr * 4 + hh] = s;
    }
    __syncthreads();
    const int j = t & 127, rp = t >> 7;
#pragma unroll
    for (int rr = 0; rr < 2; ++rr) {
        int lr = 2 * rp + rr;
        int gr = row0 + lr;
        float s = 0.f;
#pragma unroll
        for (int sg = 0; sg < NSEG; ++sg)
            s += bf2f(P.num_p[sg * SEGTOT + gr * DD + j]);
        float inv = 1.f / denl[lr * 4 + (j >> 5)];
        float cv = P.C[gr * DD + j];
        float Hv = s * inv, cb = cv - Hv;
        P.H_I[gr * DD + j] = Hv;
        P.CbI[gr * DD + j] = cb;
        Xl[lr * DD + j] = cb;
    }
    __syncthreads();
    proj4(Xl, P.guW, P.gua_src, P.gua_dst, P.hT, P.ssrc, P.sdst, row0, t);
}

// ---- finish GAT2 + deep factor heads + recon, 4 rows ----
__device__ void finish_factors4(const MegaParams& P, int row0, int t, float* sm)
{
    float* ctx = sm;           // [4][384]
    float* denl = sm + 1536;   // [4][4]
    if (t < 16) {
        int rr = t >> 2, hh = t & 3;
        float s = 0.f;
#pragma unroll
        for (int sg = 0; sg < NSEG; ++sg)
            s += P.den_p[sg * DENTOT + (row0 + rr) * NH + hh];
        denl[rr * 4 + hh] = s;
    }
    __syncthreads();
    const int j = t & 127, rp = t >> 7;
#pragma unroll
    for (int rr = 0; rr < 2; ++rr) {
        int lr = 2 * rp + rr;
        int gr = row0 + lr;
        float s = 0.f;
#pragma unroll
        for (int sg = 0; sg < NSEG; ++sg)
            s += bf2f(P.num_p[sg * SEGTOT + gr * DD + j]);
        float inv = 1.f / denl[lr * 4 + (j >> 5)];
        float ci = P.CbI[gr * DD + j];
        float cv = P.C[gr * DD + j];
        float Hv = s * inv, cu = ci - Hv;
        P.H_U[gr * DD + j] = Hv;
        P.CbU[gr * DD + j] = cu;
        ctx[lr * DEEP + j] = cv;
        ctx[lr * DEEP + DD + j] = ci;
        ctx[lr * DEEP + 2 * DD + j] = cu;
    }
    __syncthreads();
    const int w = t >> 6, l = t & 63;
    const int gr = row0 + w;
    const int b = gr / NN;
#pragma unroll
    for (int h = 0; h < HNZ; ++h) {
        const float* hw = P.head_W + h * DEEP;
        float a = 0.f;
#pragma unroll
        for (int i = 0; i < 6; ++i)
            a += ctx[w * DEEP + l + 64 * i] * hw[l + 64 * i];
        float rc = P.feat[gr * FF + l] * P.abar[(h * BB + b) * FF + l];
#pragma unroll
        for (int off = 32; off; off >>= 1) {
            a += __shfl_xor(a, off);
            rc += __shfl_xor(rc, off);
        }
        if (l == 0) {
            P.factors[h * (BB * NN) + gr] = lrelu(a + P.head_b[h]);
            P.recon[h * (BB * NN) + gr] = rc * (1.f / NN);
        }
    }
}

// ---------------- plain kernels ----------------
__global__ __launch_bounds__(256) void k_encproj_fa_w(MegaParams P) {
    __shared__ float sm[SMSZ];
    if (blockIdx.x < 1000) enc_proj4(P, blockIdx.x * 4, threadIdx.x, sm);
    else                   fa_unit(P, blockIdx.x - 1000, threadIdx.x, sm);
}
template <int MASKED>
__global__ __launch_bounds__(256) void k_attn_w(MegaParams P) {
    __shared__ float sm[SMSZ];
    attn_unit<MASKED>(P.ind_mask, P.hT, P.ssrc, P.sdst, P.num_p, P.den_p,
                      blockIdx.x, threadIdx.x, sm);
}
__global__ __launch_bounds__(256) void k_finishproj_w(MegaParams P) {
    __shared__ float sm[SMSZ];
    finish_proj4(P, blockIdx.x * 4, threadIdx.x, sm);
}
__global__ __launch_bounds__(256) void k_finishfactors_w(MegaParams P) {
    __shared__ float sm[SMSZ];
    finish_factors4(P, blockIdx.x * 4, threadIdx.x, sm);
}

extern "C" void kernel_launch(void* const* d_in, const int* in_sizes, int n_in,
                              void* d_out, int out_size, void* d_ws, size_t ws_size,
                              hipStream_t stream)
{
    float* out = (float*)d_out;
    float* ws = (float*)d_ws;

    MegaParams P;
    P.feat     = (const float*)d_in[0];
    P.ind_mask = (const int*)d_in[1];
    P.gamma    = (const float*)d_in[3];
    P.beta     = (const float*)d_in[4];
    P.mean     = (const float*)d_in[5];
    P.var      = (const float*)d_in[6];
    P.W1 = (const float*)d_in[7];
    P.b1 = (const float*)d_in[8];
    P.W2 = (const float*)d_in[9];
    P.b2 = (const float*)d_in[10];
    P.giW = (const float*)d_in[11];
    P.gia_src = (const float*)d_in[12];
    P.gia_dst = (const float*)d_in[13];
    P.guW = (const float*)d_in[14];
    P.gua_src = (const float*)d_in[15];
    P.gua_dst = (const float*)d_in[16];
    P.head_W = (const float*)d_in[17];
    P.head_b = (const float*)d_in[18];
    P.proj_W = (const float*)d_in[19];

    P.C       = out;
    P.CbI     = out + 512000;
    P.CbU     = out + 1024000;
    P.H_I     = out + 1536000;
    P.H_U     = out + 2048000;
    P.factors = out + 2560000;
    P.recon   = out + 2572000;
    P.A       = out + 2584000;

    P.hT    = (ushort_t*)ws;
    P.ssrc  = ws + 262400;
    P.sdst  = ws + 278400;
    P.den_p = ws + 294400;
    P.num_p = (ushort_t*)(ws + 422400);
    P.abar  = ws + 2470400;

    hipMemsetAsync(P.abar, 0, HNZ * BB * FF * sizeof(float), stream);

    k_encproj_fa_w<<<2500, 256, 0, stream>>>(P);
    k_attn_w<1><<<NSEG * BB * 125, 256, 0, stream>>>(P);
    k_finishproj_w<<<1000, 256, 0, stream>>>(P);
    k_attn_w<0><<<NSEG * BB * 125, 256, 0, stream>>>(P);
    k_finishfactors_w<<<1000, 256, 0, stream>>>(P);
}